// Round 4
// baseline (190.488 us; speedup 1.0000x reference)
//
#include <hip/hip_runtime.h>
#include <stdint.h>

#define B_  2
#define S_  2048
#define D_  1024
#define H_  16
#define DK_ 64

using bf16x8 = __attribute__((ext_vector_type(8))) short;
using f32x4  = __attribute__((ext_vector_type(4))) float;

__device__ __forceinline__ unsigned short f2bf(float f) {
    union { float f; uint32_t u; } v; v.f = f;
    uint32_t r = v.u + 0x7FFFu + ((v.u >> 16) & 1u);
    return (unsigned short)(r >> 16);
}
__device__ __forceinline__ float bf2f(unsigned short u) {
    union { uint32_t u; float f; } v; v.u = ((uint32_t)u) << 16;
    return v.f;
}

// async global->LDS, 16B per lane; LDS dest is wave-uniform base + lane*16
#define GLD16(G, L) __builtin_amdgcn_global_load_lds( \
    (const __attribute__((address_space(1))) void*)(const void*)(G), \
    (__attribute__((address_space(3))) void*)(void*)(L), 16, 0, 0)

// ---------------- fp32 -> bf16 convert (vectorized) ----------------
__global__ __launch_bounds__(256) void k_f32_to_bf16(const float* __restrict__ src,
                                                     unsigned short* __restrict__ dst,
                                                     int n4) {
    int i = blockIdx.x * 256 + threadIdx.x;
    if (i >= n4) return;
    float4 v = ((const float4*)src)[i];
    union { unsigned short u[4]; uint2 d; } o;
    o.u[0] = f2bf(v.x); o.u[1] = f2bf(v.y); o.u[2] = f2bf(v.z); o.u[3] = f2bf(v.w);
    ((uint2*)dst)[i] = o.d;
}

// ---------------- GEMM: C[m][n] = sum_k A[m][k] * W[n][k]  (B^T input) ------
// MODE 0: bf16 out. z=0 (Q), z=1 (K): [b][h][s][dk] head layout.
//                   z=2 (V): TRANSPOSED [b][h][dk][s].
// MODE 1: f32 out, row-major [m][n] (final output projection)
template<int MODE>
__global__ __launch_bounds__(256) void k_gemm_bt(
    const unsigned short* __restrict__ A,
    const unsigned short* __restrict__ W0,
    const unsigned short* __restrict__ W1,
    const unsigned short* __restrict__ W2,
    void* __restrict__ C0, void* __restrict__ C1, void* __restrict__ C2,
    int M, int N, int K)
{
    __shared__ __align__(16) unsigned short As[128 * 32];
    __shared__ __align__(16) unsigned short Bs[128 * 32];

    const int tid  = threadIdx.x;
    const int wid  = tid >> 6, lane = tid & 63;
    const int m16  = lane & 15, g = lane >> 4;
    const int m0   = blockIdx.x * 128, n0 = blockIdx.y * 128;
    const unsigned short* Wm = blockIdx.z == 0 ? W0 : (blockIdx.z == 1 ? W1 : W2);
    void* Cm = blockIdx.z == 0 ? C0 : (blockIdx.z == 1 ? C1 : C2);

    const int wm = (wid >> 1) * 64, wn = (wid & 1) * 64;
    const int srow = lane >> 2;          // 16 rows per 1KB chunk (64B rows)
    const int scol = (lane & 3) * 8;     // bf16 offset within row

    const f32x4 fz = {0.f, 0.f, 0.f, 0.f};
    f32x4 acc[4][4];
#pragma unroll
    for (int i = 0; i < 4; ++i)
#pragma unroll
        for (int j = 0; j < 4; ++j) acc[i][j] = fz;

    for (int k0 = 0; k0 < K; k0 += 32) {
#pragma unroll
        for (int c = 0; c < 2; ++c) {
            const int chunk = wid * 2 + c;            // 0..7
            const int row   = chunk * 16 + srow;      // 0..127
            GLD16(A  + (size_t)(m0 + row) * K + k0 + scol, As + chunk * 512);
            GLD16(Wm + (size_t)(n0 + row) * K + k0 + scol, Bs + chunk * 512);
        }
        __syncthreads();
        bf16x8 af[4], bf[4];
#pragma unroll
        for (int i = 0; i < 4; ++i)
            af[i] = *(const bf16x8*)(As + (wm + i * 16 + m16) * 32 + g * 8);
#pragma unroll
        for (int j = 0; j < 4; ++j)
            bf[j] = *(const bf16x8*)(Bs + (wn + j * 16 + m16) * 32 + g * 8);
#pragma unroll
        for (int i = 0; i < 4; ++i)
#pragma unroll
            for (int j = 0; j < 4; ++j)
                acc[i][j] = __builtin_amdgcn_mfma_f32_16x16x32_bf16(af[i], bf[j], acc[i][j], 0, 0, 0);
        __syncthreads();
    }

#pragma unroll
    for (int i = 0; i < 4; ++i) {
#pragma unroll
        for (int j = 0; j < 4; ++j) {
#pragma unroll
            for (int r = 0; r < 4; ++r) {
                const int row = m0 + wm + i * 16 + g * 4 + r;   // D row = 4*(lane>>4)+reg
                const int col = n0 + wn + j * 16 + m16;         // D col = lane&15
                const float val = acc[i][j][r];
                if (MODE == 1) {
                    ((float*)Cm)[(size_t)row * N + col] = val;
                } else {
                    const int b = row >> 11, s = row & (S_ - 1);
                    const int h = col >> 6,  dk = col & (DK_ - 1);
                    size_t idx;
                    if (blockIdx.z == 2)   // V: transposed [bh][dk][s]
                        idx = ((size_t)((b * H_ + h) * DK_ + dk)) * S_ + s;
                    else                   // Q,K: [bh][s][dk]
                        idx = ((size_t)((b * H_ + h) * S_ + s)) * DK_ + dk;
                    ((unsigned short*)Cm)[idx] = f2bf(val);
                }
            }
        }
    }
}

// ---------------- RoPE in place on [bh][s][dk] bf16 buffers ----------------
__global__ __launch_bounds__(256) void k_rope_inplace(
    unsigned short* __restrict__ qh, unsigned short* __restrict__ kh,
    const int* __restrict__ tok)
{
    const int idx = blockIdx.x * 256 + threadIdx.x;   // (bh, s, chunk-of-8)
    const int c = idx & 7;
    const int s = (idx >> 3) & (S_ - 1);
    const int b = idx >> 18;                          // total = 2^19
    const size_t off = (size_t)idx * 8;

    const float pos = (float)tok[b * S_ + s];
    float cs[4], sn[4];
#pragma unroll
    for (int i = 0; i < 4; ++i) {
        const int p = c * 4 + i;                      // pair index 0..31
        const float inv = exp2f((float)(-2 * p) * (13.287712379549449f / 64.f)); // 10000^(-2p/64)
        sincosf(pos * inv, &sn[i], &cs[i]);
    }
    bf16x8 qv = *(bf16x8*)(qh + off);
    bf16x8 kv = *(bf16x8*)(kh + off);
    bf16x8 qo, ko;
#pragma unroll
    for (int i = 0; i < 4; ++i) {
        const float q1 = bf2f((unsigned short)qv[2 * i]);
        const float q2 = bf2f((unsigned short)qv[2 * i + 1]);
        qo[2 * i]     = (short)f2bf(q1 * cs[i] - q2 * sn[i]);
        qo[2 * i + 1] = (short)f2bf(q1 * sn[i] + q2 * cs[i]);
        const float k1 = bf2f((unsigned short)kv[2 * i]);
        const float k2 = bf2f((unsigned short)kv[2 * i + 1]);
        ko[2 * i]     = (short)f2bf(k1 * cs[i] - k2 * sn[i]);
        ko[2 * i + 1] = (short)f2bf(k1 * sn[i] + k2 * cs[i]);
    }
    *(bf16x8*)(qh + off) = qo;
    *(bf16x8*)(kh + off) = ko;
}

// ---------------- causal flash attention v4 ----------------
// Block = 128 q rows (4 waves x 32), one bh. K tiles (64 kv) staged in
// double-buffered LDS (shared by 4 waves); V^T read as B-fragments DIRECTLY
// from global (L2-resident; issued at tile top, consumed ~800cyc later).
// QK^T computed SWAPPED (mfma(K,Q)) so each lane holds P[kv=g*4+r][q=m16]:
//  - P->LDS becomes 8 packed ds_write_b64 (vs 32 scalar b16)
//  - row-sum is lane-local (epilogue reduce = 2 shuffles, none in loop)
// P layout in LDS: [q][kv] bf16, 16B-slot XOR-swizzled by (q&7); PV A-frags
// read back as 4 conflict-free ds_read_b128.
__global__ __launch_bounds__(256) void k_fattn4(
    const unsigned short* __restrict__ Q,   // [bh][s][64]
    const unsigned short* __restrict__ K,   // [bh][s][64]
    const unsigned short* __restrict__ Vt,  // [bh][64][2048]
    unsigned short* __restrict__ O)         // [b][s][1024] bf16
{
    __shared__ __align__(16) unsigned short Ks[2][64 * 64];   // 8 KB each
    __shared__ __align__(16) unsigned short Pl[4][32 * 64];   // 4 KB per wave

    const int tid = threadIdx.x, wid = tid >> 6, lane = tid & 63;
    const int m16 = lane & 15, g = lane >> 4;
    const int sw = m16 & 7;
    const int bh = blockIdx.x & 31;
    const int qslot = blockIdx.x >> 5;                 // 0..15
    const int qi = qslot < 8 ? qslot : 23 - qslot;     // pair-balanced (i,i+256 sum 34)
    const int q0 = qi * 128;
    const int qw0 = q0 + wid * 32;                     // this wave's 32 rows
    const int b = bh >> 4, h = bh & 15;
    const unsigned short* Kb = K  + (size_t)bh * S_ * DK_;
    const unsigned short* Vb = Vt + (size_t)bh * DK_ * S_;

    // Q fragments: 2 m-frags x 2 k-frags, registers for whole loop
    bf16x8 qf[2][2];
#pragma unroll
    for (int mi = 0; mi < 2; ++mi) {
        const unsigned short* qp = Q + (size_t)bh * S_ * DK_
                                     + (size_t)(qw0 + mi * 16 + m16) * DK_ + g * 8;
        qf[mi][0] = *(const bf16x8*)(qp);
        qf[mi][1] = *(const bf16x8*)(qp + 32);
    }

    const f32x4 fz = {0.f, 0.f, 0.f, 0.f};
    f32x4 o[2][4];
#pragma unroll
    for (int mi = 0; mi < 2; ++mi)
#pragma unroll
        for (int i = 0; i < 4; ++i) o[mi][i] = fz;
    float ps[2] = {0.f, 0.f};              // per-lane partial row sums (q = m16)
    unsigned short* pw = Pl[wid];

    const int r8   = lane >> 3;            // staging row within 8-row chunk
    const int slot = (lane & 7) ^ r8;      // pre-swizzled source 16B slot

    // prologue: stage K tile 0 into buf 0
#pragma unroll
    for (int c = 0; c < 2; ++c) {
        const int chunk = wid * 2 + c;
        GLD16(Kb + (size_t)(chunk * 8 + r8) * DK_ + slot * 8, &Ks[0][chunk * 512]);
    }
    __syncthreads();

    const int nt = 2 * qi + 2;             // KV tiles covering q0..q0+127
    int buf = 0;
    const float kSc = 0.125f * 1.4426950408889634f;   // 1/sqrt(64) * log2(e)

    for (int t = 0; t < nt; ++t) {
        const int kv0 = t * 64;
        // stage next K tile into the other buffer (async, drains at barrier)
        if (t + 1 < nt) {
#pragma unroll
            for (int c = 0; c < 2; ++c) {
                const int chunk = wid * 2 + c;
                GLD16(Kb + (size_t)(kv0 + 64 + chunk * 8 + r8) * DK_ + slot * 8,
                      &Ks[buf ^ 1][chunk * 512]);
            }
        }

        if (kv0 <= qw0 + 31) {             // wave has unmasked work in this tile
            // V B-fragments direct from global (consumed after softmax)
            bf16x8 vf[2][4];
#pragma unroll
            for (int ks = 0; ks < 2; ++ks)
#pragma unroll
                for (int c2 = 0; c2 < 4; ++c2)
                    vf[ks][c2] = *(const bf16x8*)(Vb + (size_t)(c2 * 16 + m16) * S_
                                                  + kv0 + ks * 32 + g * 8);

            // S^T = K Q^T (swapped): sc[mi][c][r] = S[kv0+c*16+g*4+r][qw0+mi*16+m16]
            f32x4 sc[2][4];
            __builtin_amdgcn_s_setprio(1);
#pragma unroll
            for (int c = 0; c < 4; ++c) {
                const int row = c * 16 + m16;
                bf16x8 kf0 = *(const bf16x8*)(&Ks[buf][row * 64 + ((g ^ sw) << 3)]);
                bf16x8 kf1 = *(const bf16x8*)(&Ks[buf][row * 64 + (((4 + g) ^ sw) << 3)]);
#pragma unroll
                for (int mi = 0; mi < 2; ++mi) {
                    f32x4 z = fz;
                    z = __builtin_amdgcn_mfma_f32_16x16x32_bf16(kf0, qf[mi][0], z, 0, 0, 0);
                    z = __builtin_amdgcn_mfma_f32_16x16x32_bf16(kf1, qf[mi][1], z, 0, 0, 0);
                    sc[mi][c] = z;
                }
            }
            __builtin_amdgcn_s_setprio(0);

            // exp2 (folded scale), mask on diag tiles, pack pairs, b64 P-store
            const bool maskT = (kv0 + 63) > qw0;
#pragma unroll
            for (int mi = 0; mi < 2; ++mi) {
                const int qg = qw0 + mi * 16 + m16;   // this lane's q row
                const int prow = mi * 16 + m16;       // P row (local q)
#pragma unroll
                for (int c = 0; c < 4; ++c) {
                    float p[4];
#pragma unroll
                    for (int r = 0; r < 4; ++r) {
                        p[r] = exp2f(sc[mi][c][r] * kSc);
                        if (maskT && (kv0 + c * 16 + g * 4 + r > qg)) p[r] = 0.f;
                    }
                    ps[mi] += (p[0] + p[1]) + (p[2] + p[3]);
                    const uint32_t lo = (uint32_t)f2bf(p[0]) | ((uint32_t)f2bf(p[1]) << 16);
                    const uint32_t hi = (uint32_t)f2bf(p[2]) | ((uint32_t)f2bf(p[3]) << 16);
                    const int pslot = (2 * c + (g >> 1)) ^ sw;
                    uint2 w2; w2.x = lo; w2.y = hi;
                    *(uint2*)(pw + prow * 64 + pslot * 8 + (g & 1) * 4) = w2;
                }
            }
            // wave-local LDS fence (rule #18)
            asm volatile("s_waitcnt lgkmcnt(0)" ::: "memory");
            __builtin_amdgcn_sched_barrier(0);

            // O += P V : A-frags from LDS (4 b128), B-frags already in regs
            bf16x8 pa[2][2];
#pragma unroll
            for (int mi = 0; mi < 2; ++mi)
#pragma unroll
                for (int ks = 0; ks < 2; ++ks)
                    pa[mi][ks] = *(const bf16x8*)(pw + (mi * 16 + m16) * 64
                                                  + (((ks * 4 + g) ^ sw) << 3));
            __builtin_amdgcn_s_setprio(1);
#pragma unroll
            for (int mi = 0; mi < 2; ++mi)
#pragma unroll
                for (int c2 = 0; c2 < 4; ++c2) {
                    o[mi][c2] = __builtin_amdgcn_mfma_f32_16x16x32_bf16(pa[mi][0], vf[0][c2], o[mi][c2], 0, 0, 0);
                    o[mi][c2] = __builtin_amdgcn_mfma_f32_16x16x32_bf16(pa[mi][1], vf[1][c2], o[mi][c2], 0, 0, 0);
                }
            __builtin_amdgcn_s_setprio(0);
        }
        __syncthreads();                   // drains stage(t+1); buf reuse safe
        buf ^= 1;
    }

    // epilogue: denominators lane-local (q = m16): reduce over 4 g-copies
#pragma unroll
    for (int mi = 0; mi < 2; ++mi) {
        float s = ps[mi];
        s += __shfl_xor(s, 16);
        s += __shfl_xor(s, 32);
        const float inv = 1.f / s;         // valid for q = qw0 + mi*16 + m16
        float lrq[4];
#pragma unroll
        for (int r = 0; r < 4; ++r)
            lrq[r] = __shfl(inv, g * 4 + r);   // denom for q row g*4+r
#pragma unroll
        for (int c2 = 0; c2 < 4; ++c2)
#pragma unroll
            for (int r = 0; r < 4; ++r) {
                const int orow = qw0 + mi * 16 + g * 4 + r;
                const int ocol = h * DK_ + c2 * 16 + m16;
                O[((size_t)(b * S_ + orow)) * D_ + ocol] = f2bf(o[mi][c2][r] * lrq[r]);
            }
    }
}

// ---------------- host launcher ----------------
extern "C" void kernel_launch(void* const* d_in, const int* in_sizes, int n_in,
                              void* d_out, int out_size, void* d_ws, size_t ws_size,
                              hipStream_t stream) {
    (void)in_sizes; (void)n_in; (void)out_size; (void)ws_size;
    const float* x   = (const float*)d_in[0];
    const float* Wq  = (const float*)d_in[1];
    const float* Wk  = (const float*)d_in[2];
    const float* Wv  = (const float*)d_in[3];
    const float* Wo  = (const float*)d_in[4];
    const int*   tok = (const int*)d_in[5];

    char* ws = (char*)d_ws;
    const size_t MB = 1u << 20;
    unsigned short* xb  = (unsigned short*)(ws + 0 * MB);   // 8 MB  [4096][1024] bf16
    unsigned short* wqb = (unsigned short*)(ws + 8 * MB);   // 2 MB each
    unsigned short* wkb = (unsigned short*)(ws + 10 * MB);
    unsigned short* wvb = (unsigned short*)(ws + 12 * MB);
    unsigned short* wob = (unsigned short*)(ws + 14 * MB);
    unsigned short* qh  = (unsigned short*)(ws + 16 * MB);  // 8 MB  [bh][s][64]
    unsigned short* kh  = (unsigned short*)(ws + 24 * MB);
    unsigned short* vh  = (unsigned short*)(ws + 32 * MB);  // [bh][64][2048] (V^T)
    unsigned short* ao  = (unsigned short*)(ws + 40 * MB);  // 8 MB  [b][s][1024]

    // 1) convert inputs to bf16
    k_f32_to_bf16<<<4096, 256, 0, stream>>>(x,  xb,  (B_ * S_ * D_) / 4);
    k_f32_to_bf16<<<1024, 256, 0, stream>>>(Wq, wqb, (D_ * D_) / 4);
    k_f32_to_bf16<<<1024, 256, 0, stream>>>(Wk, wkb, (D_ * D_) / 4);
    k_f32_to_bf16<<<1024, 256, 0, stream>>>(Wv, wvb, (D_ * D_) / 4);
    k_f32_to_bf16<<<1024, 256, 0, stream>>>(Wo, wob, (D_ * D_) / 4);

    // 2) fused QKV projection -> head layout bf16 (V transposed)
    k_gemm_bt<0><<<dim3(32, 8, 3), 256, 0, stream>>>(
        xb, wqb, wkb, wvb, qh, kh, vh, B_ * S_, D_, D_);

    // 3) RoPE in place on Q,K
    k_rope_inplace<<<2048, 256, 0, stream>>>(qh, kh, tok);

    // 4) causal flash attention -> [b][s][e] bf16
    k_fattn4<<<dim3(512), 256, 0, stream>>>(qh, kh, vh, ao);

    // 5) output projection -> f32 d_out
    k_gemm_bt<1><<<dim3(32, 8, 1), 256, 0, stream>>>(
        ao, wob, wob, wob, d_out, d_out, d_out, B_ * S_, D_, D_);
}

// Round 6
// 133.756 us; speedup vs baseline: 1.4241x; 1.4241x over previous
//
#include <hip/hip_runtime.h>
#include <stdint.h>

#define B_  2
#define S_  2048
#define D_  1024
#define H_  16
#define DK_ 64

using bf16x8 = __attribute__((ext_vector_type(8))) short;
using f32x4  = __attribute__((ext_vector_type(4))) float;

__device__ __forceinline__ unsigned short f2bf(float f) {
    union { float f; uint32_t u; } v; v.f = f;
    uint32_t r = v.u + 0x7FFFu + ((v.u >> 16) & 1u);
    return (unsigned short)(r >> 16);
}

// pack two f32 -> one u32 of two bf16 (low = s0), RNE in HW
__device__ __forceinline__ uint32_t cvtpk(float lo, float hi) {
    uint32_t r;
    asm("v_cvt_pk_bf16_f32 %0, %1, %2" : "=v"(r) : "v"(lo), "v"(hi));
    return r;
}
// a' = {a(0-31), b(0-31)} ; b' = {a(32-63), b(32-63)}
__device__ __forceinline__ void ps32(uint32_t& a, uint32_t& b) {
    asm volatile("v_permlane32_swap_b32 %0, %1" : "+v"(a), "+v"(b));
}
// 16-lane rows: a' = {a0, b0, a2, b2} ; b' = {a1, a3 ...} (odd rows of a <-> even rows of b)
__device__ __forceinline__ void ps16(uint32_t& a, uint32_t& b) {
    asm volatile("v_permlane16_swap_b32 %0, %1" : "+v"(a), "+v"(b));
}

// async global->LDS, 16B per lane; LDS dest is wave-uniform base + lane*16
#define GLD16(G, L) __builtin_amdgcn_global_load_lds( \
    (const __attribute__((address_space(1))) void*)(const void*)(G), \
    (__attribute__((address_space(3))) void*)(void*)(L), 16, 0, 0)

// ---------------- fp32 -> bf16 convert (vectorized) ----------------
__global__ __launch_bounds__(256) void k_f32_to_bf16(const float* __restrict__ src,
                                                     unsigned short* __restrict__ dst,
                                                     int n4) {
    int i = blockIdx.x * 256 + threadIdx.x;
    if (i >= n4) return;
    float4 v = ((const float4*)src)[i];
    union { unsigned short u[4]; uint2 d; } o;
    o.u[0] = f2bf(v.x); o.u[1] = f2bf(v.y); o.u[2] = f2bf(v.z); o.u[3] = f2bf(v.w);
    ((uint2*)dst)[i] = o.d;
}

// fused 4-weight convert: grid (1024, 4)
__global__ __launch_bounds__(256) void k_wconv(
    const float* __restrict__ s0, const float* __restrict__ s1,
    const float* __restrict__ s2, const float* __restrict__ s3,
    unsigned short* __restrict__ d0, unsigned short* __restrict__ d1,
    unsigned short* __restrict__ d2, unsigned short* __restrict__ d3) {
    const int w = blockIdx.y;
    const float* s = w == 0 ? s0 : w == 1 ? s1 : w == 2 ? s2 : s3;
    unsigned short* d = w == 0 ? d0 : w == 1 ? d1 : w == 2 ? d2 : d3;
    int i = blockIdx.x * 256 + threadIdx.x;
    float4 v = ((const float4*)s)[i];
    union { unsigned short u[4]; uint2 dd; } o;
    o.u[0] = f2bf(v.x); o.u[1] = f2bf(v.y); o.u[2] = f2bf(v.z); o.u[3] = f2bf(v.w);
    ((uint2*)d)[i] = o.dd;
}

// ---------------- GEMM: C[m][n] = sum_k A[m][k] * W[n][k]  (B^T input) ------
// MODE 0: bf16 out. z=0 (Q), z=1 (K): [b][h][s][dk] head layout.
//                   z=2 (V): TRANSPOSED [b][h][dk][s].
// MODE 1: f32 out, row-major [m][n] (final output projection)
template<int MODE>
__global__ __launch_bounds__(256) void k_gemm_bt(
    const unsigned short* __restrict__ A,
    const unsigned short* __restrict__ W0,
    const unsigned short* __restrict__ W1,
    const unsigned short* __restrict__ W2,
    void* __restrict__ C0, void* __restrict__ C1, void* __restrict__ C2,
    int M, int N, int K)
{
    __shared__ __align__(16) unsigned short As[128 * 32];
    __shared__ __align__(16) unsigned short Bs[128 * 32];

    const int tid  = threadIdx.x;
    const int wid  = tid >> 6, lane = tid & 63;
    const int m16  = lane & 15, g = lane >> 4;
    const int m0   = blockIdx.x * 128, n0 = blockIdx.y * 128;
    const unsigned short* Wm = blockIdx.z == 0 ? W0 : (blockIdx.z == 1 ? W1 : W2);
    void* Cm = blockIdx.z == 0 ? C0 : (blockIdx.z == 1 ? C1 : C2);

    const int wm = (wid >> 1) * 64, wn = (wid & 1) * 64;
    const int srow = lane >> 2;
    const int scol = (lane & 3) * 8;

    const f32x4 fz = {0.f, 0.f, 0.f, 0.f};
    f32x4 acc[4][4];
#pragma unroll
    for (int i = 0; i < 4; ++i)
#pragma unroll
        for (int j = 0; j < 4; ++j) acc[i][j] = fz;

    for (int k0 = 0; k0 < K; k0 += 32) {
#pragma unroll
        for (int c = 0; c < 2; ++c) {
            const int chunk = wid * 2 + c;
            const int row   = chunk * 16 + srow;
            GLD16(A  + (size_t)(m0 + row) * K + k0 + scol, As + chunk * 512);
            GLD16(Wm + (size_t)(n0 + row) * K + k0 + scol, Bs + chunk * 512);
        }
        __syncthreads();
        bf16x8 af[4], bf[4];
#pragma unroll
        for (int i = 0; i < 4; ++i)
            af[i] = *(const bf16x8*)(As + (wm + i * 16 + m16) * 32 + g * 8);
#pragma unroll
        for (int j = 0; j < 4; ++j)
            bf[j] = *(const bf16x8*)(Bs + (wn + j * 16 + m16) * 32 + g * 8);
#pragma unroll
        for (int i = 0; i < 4; ++i)
#pragma unroll
            for (int j = 0; j < 4; ++j)
                acc[i][j] = __builtin_amdgcn_mfma_f32_16x16x32_bf16(af[i], bf[j], acc[i][j], 0, 0, 0);
        __syncthreads();
    }

#pragma unroll
    for (int i = 0; i < 4; ++i) {
#pragma unroll
        for (int j = 0; j < 4; ++j) {
#pragma unroll
            for (int r = 0; r < 4; ++r) {
                const int row = m0 + wm + i * 16 + g * 4 + r;
                const int col = n0 + wn + j * 16 + m16;
                const float val = acc[i][j][r];
                if (MODE == 1) {
                    ((float*)Cm)[(size_t)row * N + col] = val;
                } else {
                    const int b = row >> 11, s = row & (S_ - 1);
                    const int h = col >> 6,  dk = col & (DK_ - 1);
                    size_t idx;
                    if (blockIdx.z == 2)   // V: transposed [bh][dk][s]
                        idx = ((size_t)((b * H_ + h) * DK_ + dk)) * S_ + s;
                    else                   // Q,K: [bh][s][dk]
                        idx = ((size_t)((b * H_ + h) * S_ + s)) * DK_ + dk;
                    ((unsigned short*)Cm)[idx] = f2bf(val);
                }
            }
        }
    }
}

// ---------------- RoPE in place on [bh][s][dk] bf16 buffers ----------------
__global__ __launch_bounds__(256) void k_rope_inplace(
    unsigned short* __restrict__ qh, unsigned short* __restrict__ kh,
    const int* __restrict__ tok)
{
    const int idx = blockIdx.x * 256 + threadIdx.x;
    const int c = idx & 7;
    const int s = (idx >> 3) & (S_ - 1);
    const int b = idx >> 18;
    const size_t off = (size_t)idx * 8;

    const float pos = (float)tok[b * S_ + s];
    float cs[4], sn[4];
#pragma unroll
    for (int i = 0; i < 4; ++i) {
        const int p = c * 4 + i;
        const float inv = exp2f((float)(-2 * p) * (13.287712379549449f / 64.f));
        sincosf(pos * inv, &sn[i], &cs[i]);
    }
    bf16x8 qv = *(bf16x8*)(qh + off);
    bf16x8 kv = *(bf16x8*)(kh + off);
    bf16x8 qo, ko;
#pragma unroll
    for (int i = 0; i < 4; ++i) {
        union { uint32_t u; float f; } q1{(uint32_t)(unsigned short)qv[2*i] << 16};
        union { uint32_t u; float f; } q2{(uint32_t)(unsigned short)qv[2*i+1] << 16};
        qo[2 * i]     = (short)f2bf(q1.f * cs[i] - q2.f * sn[i]);
        qo[2 * i + 1] = (short)f2bf(q1.f * sn[i] + q2.f * cs[i]);
        union { uint32_t u; float f; } k1{(uint32_t)(unsigned short)kv[2*i] << 16};
        union { uint32_t u; float f; } k2{(uint32_t)(unsigned short)kv[2*i+1] << 16};
        ko[2 * i]     = (short)f2bf(k1.f * cs[i] - k2.f * sn[i]);
        ko[2 * i + 1] = (short)f2bf(k1.f * sn[i] + k2.f * cs[i]);
    }
    *(bf16x8*)(qh + off) = qo;
    *(bf16x8*)(kh + off) = ko;
}

// ---------------- causal flash attention v5b ----------------
// grid 1024 (bh=32 x qg=32), 4 waves x 16 q-rows = 64 rows/block.
// sigma-mapping: co-resident quadruples {a,15-a,16+a,31-a} sum to 66 tiles.
// K,V^T staged dbuf LDS (conflict-free swizzle), shared by 4 waves.
// P never touches LDS: swapped QK^T -> cvt_pk_bf16 -> permlane32/16_swap
// redistribute into PV A-frag layout (pure VALU).
// FIX vs v5: diag-tile causal mask applies to ALL waves (was wid<3 — wave 3's
// rows q0+48..63 see kv up to q0+63 > row, so it must mask too).
__global__ __launch_bounds__(256, 4) void k_fattn5(
    const unsigned short* __restrict__ Q,   // [bh][s][64]
    const unsigned short* __restrict__ K,   // [bh][s][64]
    const unsigned short* __restrict__ Vt,  // [bh][64][2048]
    unsigned short* __restrict__ O)         // [b][s][1024] bf16
{
    __shared__ __align__(16) unsigned short Ks[2][64 * 64];   // 8 KB each
    __shared__ __align__(16) unsigned short Vs[2][64 * 64];   // [dv][kv]

    const int tid = threadIdx.x, wid = tid >> 6, lane = tid & 63;
    const int m16 = lane & 15, g = lane >> 4;
    const int bh = blockIdx.x & 31;
    const int qg = blockIdx.x >> 5;                     // 0..31
    const int a  = qg & 7, kq = qg >> 3;
    const int qi = kq == 0 ? a : (kq == 1 ? 15 - a : (kq == 2 ? 16 + a : 31 - a));
    const int q0 = qi * 64;
    const int qw0 = q0 + wid * 16;                      // this wave's 16 rows
    const int b = bh >> 4, h = bh & 15;
    const unsigned short* Kb = K  + (size_t)bh * S_ * DK_;
    const unsigned short* Vb = Vt + (size_t)bh * DK_ * S_;

    // Q fragments (B-operand of swapped QK): lane (m16,g) = Q[qw0+m16][k]
    bf16x8 qf[2];
    {
        const unsigned short* qp = Q + (size_t)bh * S_ * DK_
                                     + (size_t)(qw0 + m16) * DK_ + g * 8;
        qf[0] = *(const bf16x8*)(qp);
        qf[1] = *(const bf16x8*)(qp + 32);
    }

    const f32x4 fz = {0.f, 0.f, 0.f, 0.f};
    f32x4 o[4];
#pragma unroll
    for (int i = 0; i < 4; ++i) o[i] = fz;
    float ps = 0.f;                     // partial row sum for q = qw0 + m16

    const int r8   = lane >> 3;         // staging row within 8-row chunk
    const int slot = (lane & 7) ^ r8;   // pre-swizzled source 16B slot

    // prologue: stage K,V tile 0 into buf 0
#pragma unroll
    for (int c = 0; c < 2; ++c) {
        const int ch = wid * 2 + c;
        GLD16(Kb + (size_t)(ch * 8 + r8) * DK_ + slot * 8, &Ks[0][ch * 512]);
        GLD16(Vb + (size_t)(ch * 8 + r8) * S_  + slot * 8, &Vs[0][ch * 512]);
    }
    __syncthreads();

    const int nt = qi + 1;
    int buf = 0;
    const float kSc = 0.125f * 1.4426950408889634f;   // 1/sqrt(DK) * log2(e)

    for (int t = 0; t < nt; ++t) {
        const int kv0 = t * 64;
        if (t + 1 < nt) {              // stage next tile (drains at barrier)
#pragma unroll
            for (int c = 0; c < 2; ++c) {
                const int ch = wid * 2 + c;
                GLD16(Kb + (size_t)(kv0 + 64 + ch * 8 + r8) * DK_ + slot * 8,
                      &Ks[buf ^ 1][ch * 512]);
                GLD16(Vb + (size_t)(ch * 8 + r8) * S_ + kv0 + 64 + slot * 8,
                      &Vs[buf ^ 1][ch * 512]);
            }
        }

        // S^T = K Q^T : lane (m16,g) reg (c,r) = S[kv0+c*16+g*4+r][qw0+m16]
        f32x4 sc[4];
        __builtin_amdgcn_s_setprio(1);
#pragma unroll
        for (int c = 0; c < 4; ++c) {
            const int row = c * 16 + m16, rr = row & 7;
            bf16x8 kf0 = *(const bf16x8*)(&Ks[buf][row * 64 + ((g ^ rr) << 3)]);
            bf16x8 kf1 = *(const bf16x8*)(&Ks[buf][row * 64 + (((4 + g) ^ rr) << 3)]);
            f32x4 z = fz;
            z = __builtin_amdgcn_mfma_f32_16x16x32_bf16(kf0, qf[0], z, 0, 0, 0);
            z = __builtin_amdgcn_mfma_f32_16x16x32_bf16(kf1, qf[1], z, 0, 0, 0);
            sc[c] = z;
        }
        __builtin_amdgcn_s_setprio(0);

        // exp2 (folded scale), causal mask on diag tile (ALL waves), pack
        const bool maskT = (t == qi);
        const int qrow = qw0 + m16;
        uint32_t pk[4][2];
#pragma unroll
        for (int c = 0; c < 4; ++c) {
            float p[4];
#pragma unroll
            for (int r = 0; r < 4; ++r) {
                float v = exp2f(sc[c][r] * kSc);
                if (maskT && (kv0 + c * 16 + g * 4 + r > qrow)) v = 0.f;
                p[r] = v;
            }
            ps += (p[0] + p[1]) + (p[2] + p[3]);
            pk[c][0] = cvtpk(p[0], p[1]);
            pk[c][1] = cvtpk(p[2], p[3]);
        }

        // permlane redistribution: P^T fragments -> P A-fragments (no LDS!)
        bf16x8 pf[2];
#pragma unroll
        for (int ks = 0; ks < 2; ++ks) {
            uint32_t ylo = pk[2 * ks][0], zlo = pk[2 * ks + 1][0];
            ps32(ylo, zlo); ps16(ylo, zlo);
            uint32_t yhi = pk[2 * ks][1], zhi = pk[2 * ks + 1][1];
            ps32(yhi, zhi); ps16(yhi, zhi);
            union { uint32_t u[4]; bf16x8 v; } fu;
            fu.u[0] = ylo; fu.u[1] = yhi; fu.u[2] = zlo; fu.u[3] = zhi;
            pf[ks] = fu.v;
        }

        // O += P V : A = pf (regs), B = V fragments from LDS
        __builtin_amdgcn_s_setprio(1);
#pragma unroll
        for (int c2 = 0; c2 < 4; ++c2) {
            const int rv = (c2 * 16 + m16) & 7;
            bf16x8 v0 = *(const bf16x8*)(&Vs[buf][(c2 * 16 + m16) * 64 + ((g ^ rv) << 3)]);
            bf16x8 v1 = *(const bf16x8*)(&Vs[buf][(c2 * 16 + m16) * 64 + (((4 + g) ^ rv) << 3)]);
            o[c2] = __builtin_amdgcn_mfma_f32_16x16x32_bf16(pf[0], v0, o[c2], 0, 0, 0);
            o[c2] = __builtin_amdgcn_mfma_f32_16x16x32_bf16(pf[1], v1, o[c2], 0, 0, 0);
        }
        __builtin_amdgcn_s_setprio(0);

        __syncthreads();               // next tile staged; buf flip safe
        buf ^= 1;
    }

    // epilogue: denominator lives at lanes with m16 = q; reduce 4 g-copies
    float s = ps;
    s += __shfl_xor(s, 16);
    s += __shfl_xor(s, 32);
    const float inv = 1.f / s;
    float lrq[4];
#pragma unroll
    for (int r = 0; r < 4; ++r)
        lrq[r] = __shfl(inv, g * 4 + r);   // denom of q row g*4+r
#pragma unroll
    for (int c2 = 0; c2 < 4; ++c2)
#pragma unroll
        for (int r = 0; r < 4; ++r) {
            const int orow = qw0 + g * 4 + r;
            const int ocol = h * DK_ + c2 * 16 + m16;
            O[((size_t)(b * S_ + orow)) * D_ + ocol] = f2bf(o[c2][r] * lrq[r]);
        }
}

// ---------------- host launcher ----------------
extern "C" void kernel_launch(void* const* d_in, const int* in_sizes, int n_in,
                              void* d_out, int out_size, void* d_ws, size_t ws_size,
                              hipStream_t stream) {
    (void)in_sizes; (void)n_in; (void)out_size; (void)ws_size;
    const float* x   = (const float*)d_in[0];
    const float* Wq  = (const float*)d_in[1];
    const float* Wk  = (const float*)d_in[2];
    const float* Wv  = (const float*)d_in[3];
    const float* Wo  = (const float*)d_in[4];
    const int*   tok = (const int*)d_in[5];

    char* ws = (char*)d_ws;
    const size_t MB = 1u << 20;
    unsigned short* xb  = (unsigned short*)(ws + 0 * MB);   // 8 MB  [4096][1024] bf16
    unsigned short* wqb = (unsigned short*)(ws + 8 * MB);   // 2 MB each
    unsigned short* wkb = (unsigned short*)(ws + 10 * MB);
    unsigned short* wvb = (unsigned short*)(ws + 12 * MB);
    unsigned short* wob = (unsigned short*)(ws + 14 * MB);
    unsigned short* qh  = (unsigned short*)(ws + 16 * MB);  // 8 MB  [bh][s][64]
    unsigned short* kh  = (unsigned short*)(ws + 24 * MB);
    unsigned short* vh  = (unsigned short*)(ws + 32 * MB);  // [bh][64][2048] (V^T)
    unsigned short* ao  = (unsigned short*)(ws + 40 * MB);  // 8 MB  [b][s][1024]

    // 1) convert inputs to bf16 (2 launches)
    k_f32_to_bf16<<<4096, 256, 0, stream>>>(x, xb, (B_ * S_ * D_) / 4);
    k_wconv<<<dim3(1024, 4), 256, 0, stream>>>(Wq, Wk, Wv, Wo, wqb, wkb, wvb, wob);

    // 2) fused QKV projection -> head layout bf16 (V transposed)
    k_gemm_bt<0><<<dim3(32, 8, 3), 256, 0, stream>>>(
        xb, wqb, wkb, wvb, qh, kh, vh, B_ * S_, D_, D_);

    // 3) RoPE in place on Q,K
    k_rope_inplace<<<2048, 256, 0, stream>>>(qh, kh, tok);

    // 4) causal flash attention -> [b][s][e] bf16
    k_fattn5<<<dim3(1024), 256, 0, stream>>>(qh, kh, vh, ao);

    // 5) output projection -> f32 d_out
    k_gemm_bt<1><<<dim3(32, 8, 1), 256, 0, stream>>>(
        ao, wob, wob, wob, d_out, d_out, d_out, B_ * S_, D_, D_);
}

// Round 7
// 130.389 us; speedup vs baseline: 1.4609x; 1.0258x over previous
//
#include <hip/hip_runtime.h>
#include <stdint.h>

#define B_  2
#define S_  2048
#define D_  1024
#define H_  16
#define DK_ 64

using bf16x8 = __attribute__((ext_vector_type(8))) short;
using f32x4  = __attribute__((ext_vector_type(4))) float;

__device__ __forceinline__ unsigned short f2bf(float f) {
    union { float f; uint32_t u; } v; v.f = f;
    uint32_t r = v.u + 0x7FFFu + ((v.u >> 16) & 1u);
    return (unsigned short)(r >> 16);
}

// pack two f32 -> one u32 of two bf16 (low = s0), RNE in HW
__device__ __forceinline__ uint32_t cvtpk(float lo, float hi) {
    uint32_t r;
    asm("v_cvt_pk_bf16_f32 %0, %1, %2" : "=v"(r) : "v"(lo), "v"(hi));
    return r;
}
// a' = {a(0-31), b(0-31)} ; b' = {a(32-63), b(32-63)}
__device__ __forceinline__ void ps32(uint32_t& a, uint32_t& b) {
    asm volatile("v_permlane32_swap_b32 %0, %1" : "+v"(a), "+v"(b));
}
// 16-lane rows: odd rows of a <-> even rows of b
__device__ __forceinline__ void ps16(uint32_t& a, uint32_t& b) {
    asm volatile("v_permlane16_swap_b32 %0, %1" : "+v"(a), "+v"(b));
}

// async global->LDS, 16B per lane; LDS dest is wave-uniform base + lane*16
#define GLD16(G, L) __builtin_amdgcn_global_load_lds( \
    (const __attribute__((address_space(1))) void*)(const void*)(G), \
    (__attribute__((address_space(3))) void*)(void*)(L), 16, 0, 0)

// ---------------- fp32 -> bf16 convert (vectorized) ----------------
__global__ __launch_bounds__(256) void k_f32_to_bf16(const float* __restrict__ src,
                                                     unsigned short* __restrict__ dst,
                                                     int n4) {
    int i = blockIdx.x * 256 + threadIdx.x;
    if (i >= n4) return;
    float4 v = ((const float4*)src)[i];
    union { unsigned short u[4]; uint2 d; } o;
    o.u[0] = f2bf(v.x); o.u[1] = f2bf(v.y); o.u[2] = f2bf(v.z); o.u[3] = f2bf(v.w);
    ((uint2*)dst)[i] = o.d;
}

// fused 4-weight convert: grid (1024, 4)
__global__ __launch_bounds__(256) void k_wconv(
    const float* __restrict__ s0, const float* __restrict__ s1,
    const float* __restrict__ s2, const float* __restrict__ s3,
    unsigned short* __restrict__ d0, unsigned short* __restrict__ d1,
    unsigned short* __restrict__ d2, unsigned short* __restrict__ d3) {
    const int w = blockIdx.y;
    const float* s = w == 0 ? s0 : w == 1 ? s1 : w == 2 ? s2 : s3;
    unsigned short* d = w == 0 ? d0 : w == 1 ? d1 : w == 2 ? d2 : d3;
    int i = blockIdx.x * 256 + threadIdx.x;
    float4 v = ((const float4*)s)[i];
    union { unsigned short u[4]; uint2 dd; } o;
    o.u[0] = f2bf(v.x); o.u[1] = f2bf(v.y); o.u[2] = f2bf(v.z); o.u[3] = f2bf(v.w);
    ((uint2*)d)[i] = o.dd;
}

// ---------------- GEMM: C[m][n] = sum_k A[m][k] * W[n][k]  (B^T input) ------
// MODE 0: bf16 out. z=0 (Q), z=1 (K): [b][h][s][dk] head layout.
//                   z=2 (V): TRANSPOSED [b][h][dk][s].
// MODE 1: f32 out, row-major [m][n] (final output projection)
template<int MODE>
__global__ __launch_bounds__(256) void k_gemm_bt(
    const unsigned short* __restrict__ A,
    const unsigned short* __restrict__ W0,
    const unsigned short* __restrict__ W1,
    const unsigned short* __restrict__ W2,
    void* __restrict__ C0, void* __restrict__ C1, void* __restrict__ C2,
    int M, int N, int K)
{
    __shared__ __align__(16) unsigned short As[128 * 32];
    __shared__ __align__(16) unsigned short Bs[128 * 32];

    const int tid  = threadIdx.x;
    const int wid  = tid >> 6, lane = tid & 63;
    const int m16  = lane & 15, g = lane >> 4;
    const int m0   = blockIdx.x * 128, n0 = blockIdx.y * 128;
    const unsigned short* Wm = blockIdx.z == 0 ? W0 : (blockIdx.z == 1 ? W1 : W2);
    void* Cm = blockIdx.z == 0 ? C0 : (blockIdx.z == 1 ? C1 : C2);

    const int wm = (wid >> 1) * 64, wn = (wid & 1) * 64;
    const int srow = lane >> 2;
    const int scol = (lane & 3) * 8;

    const f32x4 fz = {0.f, 0.f, 0.f, 0.f};
    f32x4 acc[4][4];
#pragma unroll
    for (int i = 0; i < 4; ++i)
#pragma unroll
        for (int j = 0; j < 4; ++j) acc[i][j] = fz;

    for (int k0 = 0; k0 < K; k0 += 32) {
#pragma unroll
        for (int c = 0; c < 2; ++c) {
            const int chunk = wid * 2 + c;
            const int row   = chunk * 16 + srow;
            GLD16(A  + (size_t)(m0 + row) * K + k0 + scol, As + chunk * 512);
            GLD16(Wm + (size_t)(n0 + row) * K + k0 + scol, Bs + chunk * 512);
        }
        __syncthreads();
        bf16x8 af[4], bf[4];
#pragma unroll
        for (int i = 0; i < 4; ++i)
            af[i] = *(const bf16x8*)(As + (wm + i * 16 + m16) * 32 + g * 8);
#pragma unroll
        for (int j = 0; j < 4; ++j)
            bf[j] = *(const bf16x8*)(Bs + (wn + j * 16 + m16) * 32 + g * 8);
#pragma unroll
        for (int i = 0; i < 4; ++i)
#pragma unroll
            for (int j = 0; j < 4; ++j)
                acc[i][j] = __builtin_amdgcn_mfma_f32_16x16x32_bf16(af[i], bf[j], acc[i][j], 0, 0, 0);
        __syncthreads();
    }

#pragma unroll
    for (int i = 0; i < 4; ++i) {
#pragma unroll
        for (int j = 0; j < 4; ++j) {
#pragma unroll
            for (int r = 0; r < 4; ++r) {
                const int row = m0 + wm + i * 16 + g * 4 + r;
                const int col = n0 + wn + j * 16 + m16;
                const float val = acc[i][j][r];
                if (MODE == 1) {
                    ((float*)Cm)[(size_t)row * N + col] = val;
                } else {
                    const int b = row >> 11, s = row & (S_ - 1);
                    const int h = col >> 6,  dk = col & (DK_ - 1);
                    size_t idx;
                    if (blockIdx.z == 2)   // V: transposed [bh][dk][s]
                        idx = ((size_t)((b * H_ + h) * DK_ + dk)) * S_ + s;
                    else                   // Q,K: [bh][s][dk]
                        idx = ((size_t)((b * H_ + h) * S_ + s)) * DK_ + dk;
                    ((unsigned short*)Cm)[idx] = f2bf(val);
                }
            }
        }
    }
}

// ---------------- RoPE in place on [bh][s][dk] bf16 buffers ----------------
__global__ __launch_bounds__(256) void k_rope_inplace(
    unsigned short* __restrict__ qh, unsigned short* __restrict__ kh,
    const int* __restrict__ tok)
{
    const int idx = blockIdx.x * 256 + threadIdx.x;
    const int c = idx & 7;
    const int s = (idx >> 3) & (S_ - 1);
    const int b = idx >> 18;
    const size_t off = (size_t)idx * 8;

    const float pos = (float)tok[b * S_ + s];
    float cs[4], sn[4];
#pragma unroll
    for (int i = 0; i < 4; ++i) {
        const int p = c * 4 + i;
        const float inv = exp2f((float)(-2 * p) * (13.287712379549449f / 64.f));
        sincosf(pos * inv, &sn[i], &cs[i]);
    }
    bf16x8 qv = *(bf16x8*)(qh + off);
    bf16x8 kv = *(bf16x8*)(kh + off);
    bf16x8 qo, ko;
#pragma unroll
    for (int i = 0; i < 4; ++i) {
        union { uint32_t u; float f; } q1{(uint32_t)(unsigned short)qv[2*i] << 16};
        union { uint32_t u; float f; } q2{(uint32_t)(unsigned short)qv[2*i+1] << 16};
        qo[2 * i]     = (short)f2bf(q1.f * cs[i] - q2.f * sn[i]);
        qo[2 * i + 1] = (short)f2bf(q1.f * sn[i] + q2.f * cs[i]);
        union { uint32_t u; float f; } k1{(uint32_t)(unsigned short)kv[2*i] << 16};
        union { uint32_t u; float f; } k2{(uint32_t)(unsigned short)kv[2*i+1] << 16};
        ko[2 * i]     = (short)f2bf(k1.f * cs[i] - k2.f * sn[i]);
        ko[2 * i + 1] = (short)f2bf(k1.f * sn[i] + k2.f * cs[i]);
    }
    *(bf16x8*)(qh + off) = qo;
    *(bf16x8*)(kh + off) = ko;
}

// ---------------- causal flash attention v6 ----------------
// UNIFORM-DURATION blocks: grid 512 = (bh=32, j=16); block processes q-tile
// j (j+1 kv-tiles) then q-tile 31-j (32-j kv-tiles) sequentially = 33 tiles
// for every block -> 2 blocks/CU x 4 waves = 8 waves/CU STEADY, no tail.
// Cross-phase prefetch: last tile of phase 0 stages phase 1's tile 0.
// K,V^T staged dbuf LDS (conflict-free swizzle), shared by 4 waves.
// P never touches LDS: swapped QK^T -> cvt_pk_bf16 -> permlane32/16_swap.
// V frags hoisted ABOVE softmax so ds_read latency hides under exp2/permlane.
__global__ __launch_bounds__(256, 2) void k_fattn6(
    const unsigned short* __restrict__ Q,   // [bh][s][64]
    const unsigned short* __restrict__ K,   // [bh][s][64]
    const unsigned short* __restrict__ Vt,  // [bh][64][2048]
    unsigned short* __restrict__ O)         // [b][s][1024] bf16
{
    __shared__ __align__(16) unsigned short Ks[2][64 * 64];   // 8 KB each
    __shared__ __align__(16) unsigned short Vs[2][64 * 64];   // [dv][kv]

    const int tid = threadIdx.x, wid = tid >> 6, lane = tid & 63;
    const int m16 = lane & 15, g = lane >> 4;
    const int bh = blockIdx.x & 31;
    const int j  = blockIdx.x >> 5;                     // 0..15
    const int b = bh >> 4, h = bh & 15;
    const unsigned short* Qb = Q  + (size_t)bh * S_ * DK_;
    const unsigned short* Kb = K  + (size_t)bh * S_ * DK_;
    const unsigned short* Vb = Vt + (size_t)bh * DK_ * S_;

    const int r8   = lane >> 3;         // staging row within 8-row chunk
    const int slot = (lane & 7) ^ r8;   // pre-swizzled source 16B slot
    const int ch0  = wid * 2, ch1 = wid * 2 + 1;

    const f32x4 fz = {0.f, 0.f, 0.f, 0.f};
    const float kSc = 0.125f * 1.4426950408889634f;   // 1/sqrt(DK) * log2(e)

    // prologue: stage phase-0 tile 0 into buf 0
    GLD16(Kb + (size_t)(ch0 * 8 + r8) * DK_ + slot * 8, &Ks[0][ch0 * 512]);
    GLD16(Kb + (size_t)(ch1 * 8 + r8) * DK_ + slot * 8, &Ks[0][ch1 * 512]);
    GLD16(Vb + (size_t)(ch0 * 8 + r8) * S_  + slot * 8, &Vs[0][ch0 * 512]);
    GLD16(Vb + (size_t)(ch1 * 8 + r8) * S_  + slot * 8, &Vs[0][ch1 * 512]);
    __syncthreads();

    int buf = 0;
#pragma unroll
    for (int ph = 0; ph < 2; ++ph) {
        const int qi = ph ? 31 - j : j;
        const int q0 = qi * 64;
        const int qw0 = q0 + wid * 16;                  // this wave's 16 rows

        // Q fragments (B-operand of swapped QK): lane (m16,g) = Q[qw0+m16][k]
        bf16x8 qf[2];
        {
            const unsigned short* qp = Qb + (size_t)(qw0 + m16) * DK_ + g * 8;
            qf[0] = *(const bf16x8*)(qp);
            qf[1] = *(const bf16x8*)(qp + 32);
        }

        f32x4 o[4];
#pragma unroll
        for (int i = 0; i < 4; ++i) o[i] = fz;
        float ps = 0.f;                 // partial row sum for q = qw0 + m16

        const int nt = qi + 1;
        for (int t = 0; t < nt; ++t) {
            const int kv0 = t * 64;
            // stage next tile: same phase t+1, or phase 1 tile 0 from phase 0's end
            int nkv0 = -1;
            if (t + 1 < nt)      nkv0 = kv0 + 64;
            else if (ph == 0)    nkv0 = 0;
            if (nkv0 >= 0) {
                GLD16(Kb + (size_t)(nkv0 + ch0 * 8 + r8) * DK_ + slot * 8, &Ks[buf ^ 1][ch0 * 512]);
                GLD16(Kb + (size_t)(nkv0 + ch1 * 8 + r8) * DK_ + slot * 8, &Ks[buf ^ 1][ch1 * 512]);
                GLD16(Vb + (size_t)(ch0 * 8 + r8) * S_ + nkv0 + slot * 8, &Vs[buf ^ 1][ch0 * 512]);
                GLD16(Vb + (size_t)(ch1 * 8 + r8) * S_ + nkv0 + slot * 8, &Vs[buf ^ 1][ch1 * 512]);
            }

            // S^T = K Q^T : lane (m16,g) reg (c,r) = S[kv0+c*16+g*4+r][qw0+m16]
            f32x4 sc[4];
            __builtin_amdgcn_s_setprio(1);
#pragma unroll
            for (int c = 0; c < 4; ++c) {
                const int row = c * 16 + m16, rr = row & 7;
                bf16x8 kf0 = *(const bf16x8*)(&Ks[buf][row * 64 + ((g ^ rr) << 3)]);
                bf16x8 kf1 = *(const bf16x8*)(&Ks[buf][row * 64 + (((4 + g) ^ rr) << 3)]);
                f32x4 z = fz;
                z = __builtin_amdgcn_mfma_f32_16x16x32_bf16(kf0, qf[0], z, 0, 0, 0);
                z = __builtin_amdgcn_mfma_f32_16x16x32_bf16(kf1, qf[1], z, 0, 0, 0);
                sc[c] = z;
            }
            __builtin_amdgcn_s_setprio(0);

            // V B-frags hoisted above softmax (latency hides under exp/permlane)
            bf16x8 vf[2][4];
#pragma unroll
            for (int c2 = 0; c2 < 4; ++c2) {
                const int rv = (c2 * 16 + m16) & 7;
                vf[0][c2] = *(const bf16x8*)(&Vs[buf][(c2 * 16 + m16) * 64 + ((g ^ rv) << 3)]);
                vf[1][c2] = *(const bf16x8*)(&Vs[buf][(c2 * 16 + m16) * 64 + (((4 + g) ^ rv) << 3)]);
            }

            // exp2 (folded scale), causal mask on diag tile (ALL waves), pack
            const bool maskT = (t == qi);
            const int qrow = qw0 + m16;
            uint32_t pk[4][2];
#pragma unroll
            for (int c = 0; c < 4; ++c) {
                float p[4];
#pragma unroll
                for (int r = 0; r < 4; ++r) {
                    float v = exp2f(sc[c][r] * kSc);
                    if (maskT && (kv0 + c * 16 + g * 4 + r > qrow)) v = 0.f;
                    p[r] = v;
                }
                ps += (p[0] + p[1]) + (p[2] + p[3]);
                pk[c][0] = cvtpk(p[0], p[1]);
                pk[c][1] = cvtpk(p[2], p[3]);
            }

            // permlane redistribution: P^T fragments -> P A-fragments (no LDS)
            bf16x8 pf[2];
#pragma unroll
            for (int ks = 0; ks < 2; ++ks) {
                uint32_t ylo = pk[2 * ks][0], zlo = pk[2 * ks + 1][0];
                ps32(ylo, zlo); ps16(ylo, zlo);
                uint32_t yhi = pk[2 * ks][1], zhi = pk[2 * ks + 1][1];
                ps32(yhi, zhi); ps16(yhi, zhi);
                union { uint32_t u[4]; bf16x8 v; } fu;
                fu.u[0] = ylo; fu.u[1] = yhi; fu.u[2] = zlo; fu.u[3] = zhi;
                pf[ks] = fu.v;
            }

            // O += P V
            __builtin_amdgcn_s_setprio(1);
#pragma unroll
            for (int c2 = 0; c2 < 4; ++c2) {
                o[c2] = __builtin_amdgcn_mfma_f32_16x16x32_bf16(pf[0], vf[0][c2], o[c2], 0, 0, 0);
                o[c2] = __builtin_amdgcn_mfma_f32_16x16x32_bf16(pf[1], vf[1][c2], o[c2], 0, 0, 0);
            }
            __builtin_amdgcn_s_setprio(0);

            __syncthreads();           // next tile staged; buf flip safe
            buf ^= 1;
        }

        // epilogue: denominator lives at lanes with m16 = q; reduce 4 g-copies
        float s = ps;
        s += __shfl_xor(s, 16);
        s += __shfl_xor(s, 32);
        const float inv = 1.f / s;
        float lrq[4];
#pragma unroll
        for (int r = 0; r < 4; ++r)
            lrq[r] = __shfl(inv, g * 4 + r);   // denom of q row g*4+r
#pragma unroll
        for (int c2 = 0; c2 < 4; ++c2)
#pragma unroll
            for (int r = 0; r < 4; ++r) {
                const int orow = qw0 + g * 4 + r;
                const int ocol = h * DK_ + c2 * 16 + m16;
                O[((size_t)(b * S_ + orow)) * D_ + ocol] = f2bf(o[c2][r] * lrq[r]);
            }
    }
}

// ---------------- host launcher ----------------
extern "C" void kernel_launch(void* const* d_in, const int* in_sizes, int n_in,
                              void* d_out, int out_size, void* d_ws, size_t ws_size,
                              hipStream_t stream) {
    (void)in_sizes; (void)n_in; (void)out_size; (void)ws_size;
    const float* x   = (const float*)d_in[0];
    const float* Wq  = (const float*)d_in[1];
    const float* Wk  = (const float*)d_in[2];
    const float* Wv  = (const float*)d_in[3];
    const float* Wo  = (const float*)d_in[4];
    const int*   tok = (const int*)d_in[5];

    char* ws = (char*)d_ws;
    const size_t MB = 1u << 20;
    unsigned short* xb  = (unsigned short*)(ws + 0 * MB);   // 8 MB  [4096][1024] bf16
    unsigned short* wqb = (unsigned short*)(ws + 8 * MB);   // 2 MB each
    unsigned short* wkb = (unsigned short*)(ws + 10 * MB);
    unsigned short* wvb = (unsigned short*)(ws + 12 * MB);
    unsigned short* wob = (unsigned short*)(ws + 14 * MB);
    unsigned short* qh  = (unsigned short*)(ws + 16 * MB);  // 8 MB  [bh][s][64]
    unsigned short* kh  = (unsigned short*)(ws + 24 * MB);
    unsigned short* vh  = (unsigned short*)(ws + 32 * MB);  // [bh][64][2048] (V^T)
    unsigned short* ao  = (unsigned short*)(ws + 40 * MB);  // 8 MB  [b][s][1024]

    // 1) convert inputs to bf16 (2 launches)
    k_f32_to_bf16<<<4096, 256, 0, stream>>>(x, xb, (B_ * S_ * D_) / 4);
    k_wconv<<<dim3(1024, 4), 256, 0, stream>>>(Wq, Wk, Wv, Wo, wqb, wkb, wvb, wob);

    // 2) fused QKV projection -> head layout bf16 (V transposed)
    k_gemm_bt<0><<<dim3(32, 8, 3), 256, 0, stream>>>(
        xb, wqb, wkb, wvb, qh, kh, vh, B_ * S_, D_, D_);

    // 3) RoPE in place on Q,K
    k_rope_inplace<<<2048, 256, 0, stream>>>(qh, kh, tok);

    // 4) causal flash attention -> [b][s][e] bf16
    k_fattn6<<<dim3(512), 256, 0, stream>>>(qh, kh, vh, ao);

    // 5) output projection -> f32 d_out
    k_gemm_bt<1><<<dim3(32, 8, 1), 256, 0, stream>>>(
        ao, wob, wob, wob, d_out, d_out, d_out, B_ * S_, D_, D_);
}

// Round 8
// 122.615 us; speedup vs baseline: 1.5535x; 1.0634x over previous
//
#include <hip/hip_runtime.h>
#include <stdint.h>

#define B_  2
#define S_  2048
#define D_  1024
#define H_  16
#define DK_ 64

using bf16x8 = __attribute__((ext_vector_type(8))) short;
using f32x4  = __attribute__((ext_vector_type(4))) float;

__device__ __forceinline__ unsigned short f2bf(float f) {
    union { float f; uint32_t u; } v; v.f = f;
    uint32_t r = v.u + 0x7FFFu + ((v.u >> 16) & 1u);
    return (unsigned short)(r >> 16);
}

// pack two f32 -> one u32 of two bf16 (low = s0), RNE in HW
__device__ __forceinline__ uint32_t cvtpk(float lo, float hi) {
    uint32_t r;
    asm("v_cvt_pk_bf16_f32 %0, %1, %2" : "=v"(r) : "v"(lo), "v"(hi));
    return r;
}
// a' = {a(0-31), b(0-31)} ; b' = {a(32-63), b(32-63)}
__device__ __forceinline__ void ps32(uint32_t& a, uint32_t& b) {
    asm volatile("v_permlane32_swap_b32 %0, %1" : "+v"(a), "+v"(b));
}
// 16-lane rows: odd rows of a <-> even rows of b
__device__ __forceinline__ void ps16(uint32_t& a, uint32_t& b) {
    asm volatile("v_permlane16_swap_b32 %0, %1" : "+v"(a), "+v"(b));
}

// async global->LDS, 16B per lane; LDS dest is wave-uniform base + lane*16
#define GLD16(G, L) __builtin_amdgcn_global_load_lds( \
    (const __attribute__((address_space(1))) void*)(const void*)(G), \
    (__attribute__((address_space(3))) void*)(void*)(L), 16, 0, 0)

// ---------------- fp32 -> bf16 convert (vectorized) ----------------
__global__ __launch_bounds__(256) void k_f32_to_bf16(const float* __restrict__ src,
                                                     unsigned short* __restrict__ dst,
                                                     int n4) {
    int i = blockIdx.x * 256 + threadIdx.x;
    if (i >= n4) return;
    float4 v = ((const float4*)src)[i];
    union { unsigned short u[4]; uint2 d; } o;
    o.u[0] = f2bf(v.x); o.u[1] = f2bf(v.y); o.u[2] = f2bf(v.z); o.u[3] = f2bf(v.w);
    ((uint2*)dst)[i] = o.d;
}

// fused 4-weight convert: grid (1024, 4)
__global__ __launch_bounds__(256) void k_wconv(
    const float* __restrict__ s0, const float* __restrict__ s1,
    const float* __restrict__ s2, const float* __restrict__ s3,
    unsigned short* __restrict__ d0, unsigned short* __restrict__ d1,
    unsigned short* __restrict__ d2, unsigned short* __restrict__ d3) {
    const int w = blockIdx.y;
    const float* s = w == 0 ? s0 : w == 1 ? s1 : w == 2 ? s2 : s3;
    unsigned short* d = w == 0 ? d0 : w == 1 ? d1 : w == 2 ? d2 : d3;
    int i = blockIdx.x * 256 + threadIdx.x;
    float4 v = ((const float4*)s)[i];
    union { unsigned short u[4]; uint2 dd; } o;
    o.u[0] = f2bf(v.x); o.u[1] = f2bf(v.y); o.u[2] = f2bf(v.z); o.u[3] = f2bf(v.w);
    ((uint2*)d)[i] = o.dd;
}

// ---------------- GEMM: C[m][n] = sum_k A[m][k] * W[n][k]  (B^T input) ------
// v8: (a) conflict-free LDS: read slot = g ^ ((m16>>1)&3), staged with
//     pre-swizzled global source col16 = (lane&3) ^ ((lane>>3)&3) (involution,
//     both-sides). Quarter-wave hits all 8 bank-groups, 2 lanes each.
//     (b) 2-phase prefetch: stage(t+1) -> compute(t) -> one barrier -> flip.
// MODE 0: bf16 out. z=0 (Q), z=1 (K): [b][h][s][dk] head layout.
//                   z=2 (V): TRANSPOSED [b][h][dk][s].
// MODE 1: f32 out, row-major [m][n] (final output projection)
template<int MODE>
__global__ __launch_bounds__(256) void k_gemm_bt(
    const unsigned short* __restrict__ A,
    const unsigned short* __restrict__ W0,
    const unsigned short* __restrict__ W1,
    const unsigned short* __restrict__ W2,
    void* __restrict__ C0, void* __restrict__ C1, void* __restrict__ C2,
    int M, int N, int K)
{
    __shared__ __align__(16) unsigned short As[2][128 * 32];
    __shared__ __align__(16) unsigned short Bs[2][128 * 32];

    const int tid  = threadIdx.x;
    const int wid  = tid >> 6, lane = tid & 63;
    const int m16  = lane & 15, g = lane >> 4;
    const int m0   = blockIdx.x * 128, n0 = blockIdx.y * 128;
    const unsigned short* Wm = blockIdx.z == 0 ? W0 : (blockIdx.z == 1 ? W1 : W2);
    void* Cm = blockIdx.z == 0 ? C0 : (blockIdx.z == 1 ? C1 : C2);

    const int wm = (wid >> 1) * 64, wn = (wid & 1) * 64;
    const int srow = lane >> 2;                              // row in 16-row chunk
    const int scol = ((lane & 3) ^ ((lane >> 3) & 3)) * 8;   // pre-swizzled src col
    const int sw8  = (m16 >> 1) & 3;                         // read-side XOR

    const f32x4 fz = {0.f, 0.f, 0.f, 0.f};
    f32x4 acc[4][4];
#pragma unroll
    for (int i = 0; i < 4; ++i)
#pragma unroll
        for (int j = 0; j < 4; ++j) acc[i][j] = fz;

    // prologue: stage k0 = 0 into buf 0
#pragma unroll
    for (int c = 0; c < 2; ++c) {
        const int chunk = wid * 2 + c;
        const int row   = chunk * 16 + srow;
        GLD16(A  + (size_t)(m0 + row) * K + scol, &As[0][chunk * 512]);
        GLD16(Wm + (size_t)(n0 + row) * K + scol, &Bs[0][chunk * 512]);
    }
    __syncthreads();

    int buf = 0;
    for (int k0 = 0; k0 < K; k0 += 32) {
        if (k0 + 32 < K) {             // stage next K-slab into other buffer
#pragma unroll
            for (int c = 0; c < 2; ++c) {
                const int chunk = wid * 2 + c;
                const int row   = chunk * 16 + srow;
                GLD16(A  + (size_t)(m0 + row) * K + k0 + 32 + scol, &As[buf ^ 1][chunk * 512]);
                GLD16(Wm + (size_t)(n0 + row) * K + k0 + 32 + scol, &Bs[buf ^ 1][chunk * 512]);
            }
        }
        bf16x8 af[4], bf[4];
#pragma unroll
        for (int i = 0; i < 4; ++i)
            af[i] = *(const bf16x8*)(&As[buf][(wm + i * 16 + m16) * 32 + ((g ^ sw8) * 8)]);
#pragma unroll
        for (int j = 0; j < 4; ++j)
            bf[j] = *(const bf16x8*)(&Bs[buf][(wn + j * 16 + m16) * 32 + ((g ^ sw8) * 8)]);
#pragma unroll
        for (int i = 0; i < 4; ++i)
#pragma unroll
            for (int j = 0; j < 4; ++j)
                acc[i][j] = __builtin_amdgcn_mfma_f32_16x16x32_bf16(af[i], bf[j], acc[i][j], 0, 0, 0);
        __syncthreads();               // readers done + next stage drained
        buf ^= 1;
    }

#pragma unroll
    for (int i = 0; i < 4; ++i) {
#pragma unroll
        for (int j = 0; j < 4; ++j) {
#pragma unroll
            for (int r = 0; r < 4; ++r) {
                const int row = m0 + wm + i * 16 + g * 4 + r;
                const int col = n0 + wn + j * 16 + m16;
                const float val = acc[i][j][r];
                if (MODE == 1) {
                    ((float*)Cm)[(size_t)row * N + col] = val;
                } else {
                    const int b = row >> 11, s = row & (S_ - 1);
                    const int h = col >> 6,  dk = col & (DK_ - 1);
                    size_t idx;
                    if (blockIdx.z == 2)   // V: transposed [bh][dk][s]
                        idx = ((size_t)((b * H_ + h) * DK_ + dk)) * S_ + s;
                    else                   // Q,K: [bh][s][dk]
                        idx = ((size_t)((b * H_ + h) * S_ + s)) * DK_ + dk;
                    ((unsigned short*)Cm)[idx] = f2bf(val);
                }
            }
        }
    }
}

// ---------------- RoPE in place on [bh][s][dk] bf16 buffers ----------------
__global__ __launch_bounds__(256) void k_rope_inplace(
    unsigned short* __restrict__ qh, unsigned short* __restrict__ kh,
    const int* __restrict__ tok)
{
    const int idx = blockIdx.x * 256 + threadIdx.x;
    const int c = idx & 7;
    const int s = (idx >> 3) & (S_ - 1);
    const int b = idx >> 18;
    const size_t off = (size_t)idx * 8;

    const float pos = (float)tok[b * S_ + s];
    float cs[4], sn[4];
#pragma unroll
    for (int i = 0; i < 4; ++i) {
        const int p = c * 4 + i;
        const float inv = exp2f((float)(-2 * p) * (13.287712379549449f / 64.f));
        sincosf(pos * inv, &sn[i], &cs[i]);
    }
    bf16x8 qv = *(bf16x8*)(qh + off);
    bf16x8 kv = *(bf16x8*)(kh + off);
    bf16x8 qo, ko;
#pragma unroll
    for (int i = 0; i < 4; ++i) {
        union { uint32_t u; float f; } q1{(uint32_t)(unsigned short)qv[2*i] << 16};
        union { uint32_t u; float f; } q2{(uint32_t)(unsigned short)qv[2*i+1] << 16};
        qo[2 * i]     = (short)f2bf(q1.f * cs[i] - q2.f * sn[i]);
        qo[2 * i + 1] = (short)f2bf(q1.f * sn[i] + q2.f * cs[i]);
        union { uint32_t u; float f; } k1{(uint32_t)(unsigned short)kv[2*i] << 16};
        union { uint32_t u; float f; } k2{(uint32_t)(unsigned short)kv[2*i+1] << 16};
        ko[2 * i]     = (short)f2bf(k1.f * cs[i] - k2.f * sn[i]);
        ko[2 * i + 1] = (short)f2bf(k1.f * sn[i] + k2.f * cs[i]);
    }
    *(bf16x8*)(qh + off) = qo;
    *(bf16x8*)(kh + off) = ko;
}

// ---------------- causal flash attention v6 (unchanged from round 7) -------
__global__ __launch_bounds__(256, 2) void k_fattn6(
    const unsigned short* __restrict__ Q,   // [bh][s][64]
    const unsigned short* __restrict__ K,   // [bh][s][64]
    const unsigned short* __restrict__ Vt,  // [bh][64][2048]
    unsigned short* __restrict__ O)         // [b][s][1024] bf16
{
    __shared__ __align__(16) unsigned short Ks[2][64 * 64];
    __shared__ __align__(16) unsigned short Vs[2][64 * 64];

    const int tid = threadIdx.x, wid = tid >> 6, lane = tid & 63;
    const int m16 = lane & 15, g = lane >> 4;
    const int bh = blockIdx.x & 31;
    const int j  = blockIdx.x >> 5;                     // 0..15
    const int b = bh >> 4, h = bh & 15;
    const unsigned short* Qb = Q  + (size_t)bh * S_ * DK_;
    const unsigned short* Kb = K  + (size_t)bh * S_ * DK_;
    const unsigned short* Vb = Vt + (size_t)bh * DK_ * S_;

    const int r8   = lane >> 3;
    const int slot = (lane & 7) ^ r8;
    const int ch0  = wid * 2, ch1 = wid * 2 + 1;

    const f32x4 fz = {0.f, 0.f, 0.f, 0.f};
    const float kSc = 0.125f * 1.4426950408889634f;

    GLD16(Kb + (size_t)(ch0 * 8 + r8) * DK_ + slot * 8, &Ks[0][ch0 * 512]);
    GLD16(Kb + (size_t)(ch1 * 8 + r8) * DK_ + slot * 8, &Ks[0][ch1 * 512]);
    GLD16(Vb + (size_t)(ch0 * 8 + r8) * S_  + slot * 8, &Vs[0][ch0 * 512]);
    GLD16(Vb + (size_t)(ch1 * 8 + r8) * S_  + slot * 8, &Vs[0][ch1 * 512]);
    __syncthreads();

    int buf = 0;
#pragma unroll
    for (int ph = 0; ph < 2; ++ph) {
        const int qi = ph ? 31 - j : j;
        const int q0 = qi * 64;
        const int qw0 = q0 + wid * 16;

        bf16x8 qf[2];
        {
            const unsigned short* qp = Qb + (size_t)(qw0 + m16) * DK_ + g * 8;
            qf[0] = *(const bf16x8*)(qp);
            qf[1] = *(const bf16x8*)(qp + 32);
        }

        f32x4 o[4];
#pragma unroll
        for (int i = 0; i < 4; ++i) o[i] = fz;
        float ps = 0.f;

        const int nt = qi + 1;
        for (int t = 0; t < nt; ++t) {
            const int kv0 = t * 64;
            int nkv0 = -1;
            if (t + 1 < nt)      nkv0 = kv0 + 64;
            else if (ph == 0)    nkv0 = 0;
            if (nkv0 >= 0) {
                GLD16(Kb + (size_t)(nkv0 + ch0 * 8 + r8) * DK_ + slot * 8, &Ks[buf ^ 1][ch0 * 512]);
                GLD16(Kb + (size_t)(nkv0 + ch1 * 8 + r8) * DK_ + slot * 8, &Ks[buf ^ 1][ch1 * 512]);
                GLD16(Vb + (size_t)(ch0 * 8 + r8) * S_ + nkv0 + slot * 8, &Vs[buf ^ 1][ch0 * 512]);
                GLD16(Vb + (size_t)(ch1 * 8 + r8) * S_ + nkv0 + slot * 8, &Vs[buf ^ 1][ch1 * 512]);
            }

            f32x4 sc[4];
            __builtin_amdgcn_s_setprio(1);
#pragma unroll
            for (int c = 0; c < 4; ++c) {
                const int row = c * 16 + m16, rr = row & 7;
                bf16x8 kf0 = *(const bf16x8*)(&Ks[buf][row * 64 + ((g ^ rr) << 3)]);
                bf16x8 kf1 = *(const bf16x8*)(&Ks[buf][row * 64 + (((4 + g) ^ rr) << 3)]);
                f32x4 z = fz;
                z = __builtin_amdgcn_mfma_f32_16x16x32_bf16(kf0, qf[0], z, 0, 0, 0);
                z = __builtin_amdgcn_mfma_f32_16x16x32_bf16(kf1, qf[1], z, 0, 0, 0);
                sc[c] = z;
            }
            __builtin_amdgcn_s_setprio(0);

            bf16x8 vf[2][4];
#pragma unroll
            for (int c2 = 0; c2 < 4; ++c2) {
                const int rv = (c2 * 16 + m16) & 7;
                vf[0][c2] = *(const bf16x8*)(&Vs[buf][(c2 * 16 + m16) * 64 + ((g ^ rv) << 3)]);
                vf[1][c2] = *(const bf16x8*)(&Vs[buf][(c2 * 16 + m16) * 64 + (((4 + g) ^ rv) << 3)]);
            }

            const bool maskT = (t == qi);
            const int qrow = qw0 + m16;
            uint32_t pk[4][2];
#pragma unroll
            for (int c = 0; c < 4; ++c) {
                float p[4];
#pragma unroll
                for (int r = 0; r < 4; ++r) {
                    float v = exp2f(sc[c][r] * kSc);
                    if (maskT && (kv0 + c * 16 + g * 4 + r > qrow)) v = 0.f;
                    p[r] = v;
                }
                ps += (p[0] + p[1]) + (p[2] + p[3]);
                pk[c][0] = cvtpk(p[0], p[1]);
                pk[c][1] = cvtpk(p[2], p[3]);
            }

            bf16x8 pf[2];
#pragma unroll
            for (int ks = 0; ks < 2; ++ks) {
                uint32_t ylo = pk[2 * ks][0], zlo = pk[2 * ks + 1][0];
                ps32(ylo, zlo); ps16(ylo, zlo);
                uint32_t yhi = pk[2 * ks][1], zhi = pk[2 * ks + 1][1];
                ps32(yhi, zhi); ps16(yhi, zhi);
                union { uint32_t u[4]; bf16x8 v; } fu;
                fu.u[0] = ylo; fu.u[1] = yhi; fu.u[2] = zlo; fu.u[3] = zhi;
                pf[ks] = fu.v;
            }

            __builtin_amdgcn_s_setprio(1);
#pragma unroll
            for (int c2 = 0; c2 < 4; ++c2) {
                o[c2] = __builtin_amdgcn_mfma_f32_16x16x32_bf16(pf[0], vf[0][c2], o[c2], 0, 0, 0);
                o[c2] = __builtin_amdgcn_mfma_f32_16x16x32_bf16(pf[1], vf[1][c2], o[c2], 0, 0, 0);
            }
            __builtin_amdgcn_s_setprio(0);

            __syncthreads();
            buf ^= 1;
        }

        float s = ps;
        s += __shfl_xor(s, 16);
        s += __shfl_xor(s, 32);
        const float inv = 1.f / s;
        float lrq[4];
#pragma unroll
        for (int r = 0; r < 4; ++r)
            lrq[r] = __shfl(inv, g * 4 + r);
#pragma unroll
        for (int c2 = 0; c2 < 4; ++c2)
#pragma unroll
            for (int r = 0; r < 4; ++r) {
                const int orow = qw0 + g * 4 + r;
                const int ocol = h * DK_ + c2 * 16 + m16;
                O[((size_t)(b * S_ + orow)) * D_ + ocol] = f2bf(o[c2][r] * lrq[r]);
            }
    }
}

// ---------------- host launcher ----------------
extern "C" void kernel_launch(void* const* d_in, const int* in_sizes, int n_in,
                              void* d_out, int out_size, void* d_ws, size_t ws_size,
                              hipStream_t stream) {
    (void)in_sizes; (void)n_in; (void)out_size; (void)ws_size;
    const float* x   = (const float*)d_in[0];
    const float* Wq  = (const float*)d_in[1];
    const float* Wk  = (const float*)d_in[2];
    const float* Wv  = (const float*)d_in[3];
    const float* Wo  = (const float*)d_in[4];
    const int*   tok = (const int*)d_in[5];

    char* ws = (char*)d_ws;
    const size_t MB = 1u << 20;
    unsigned short* xb  = (unsigned short*)(ws + 0 * MB);   // 8 MB  [4096][1024] bf16
    unsigned short* wqb = (unsigned short*)(ws + 8 * MB);   // 2 MB each
    unsigned short* wkb = (unsigned short*)(ws + 10 * MB);
    unsigned short* wvb = (unsigned short*)(ws + 12 * MB);
    unsigned short* wob = (unsigned short*)(ws + 14 * MB);
    unsigned short* qh  = (unsigned short*)(ws + 16 * MB);  // 8 MB  [bh][s][64]
    unsigned short* kh  = (unsigned short*)(ws + 24 * MB);
    unsigned short* vh  = (unsigned short*)(ws + 32 * MB);  // [bh][64][2048] (V^T)
    unsigned short* ao  = (unsigned short*)(ws + 40 * MB);  // 8 MB  [b][s][1024]

    // 1) convert inputs to bf16 (2 launches)
    k_f32_to_bf16<<<4096, 256, 0, stream>>>(x, xb, (B_ * S_ * D_) / 4);
    k_wconv<<<dim3(1024, 4), 256, 0, stream>>>(Wq, Wk, Wv, Wo, wqb, wkb, wvb, wob);

    // 2) fused QKV projection -> head layout bf16 (V transposed)
    k_gemm_bt<0><<<dim3(32, 8, 3), 256, 0, stream>>>(
        xb, wqb, wkb, wvb, qh, kh, vh, B_ * S_, D_, D_);

    // 3) RoPE in place on Q,K
    k_rope_inplace<<<2048, 256, 0, stream>>>(qh, kh, tok);

    // 4) causal flash attention -> [b][s][e] bf16
    k_fattn6<<<dim3(512), 256, 0, stream>>>(qh, kh, vh, ao);

    // 5) output projection -> f32 d_out
    k_gemm_bt<1><<<dim3(32, 8, 1), 256, 0, stream>>>(
        ao, wob, wob, wob, d_out, d_out, d_out, B_ * S_, D_, D_);
}